// Round 2
// baseline (78.889 us; speedup 1.0000x reference)
//
#include <hip/hip_runtime.h>

// InstanceSegmentationLoss — 2-dispatch form (R3-proven structure).
//
// Reference == 33x33 joint histogram J[p][t] over 4.19M pixels + O(33^2) IoU.
//
// Timed-region model (R1): ~44 us harness 256 MiB d_ws zero-fill (not ours),
// ~34 us controllable slice = hist (~6-9, HBM-read floor 5.3 us; the fill
// evicts LLC + leaves dirty writeback competing with our reads) + finalize
// (~3-4, LLC-latency-bound) + flush atomics + harness memsets/gaps.
//
// R2 changes (squeeze the slice):
//   - u64-packed flush: bin pairs (2j,2j+1) in one 64-bit atomicAdd ->
//     140K atomics instead of 279K. No carry hazard: each half's total
//     <= 4.19M << 2^32 (true also for the cross-replica sum in finalize).
//   - NREP 8 -> 4 with u64 layout: finalize reduce = 545 slots x 4 loads
//     (one LLC round trip for the block), re-zero 18 KB.
//
// Cross-dispatch data moves via agent-scope atomics executed at the LLC
// (bypassing non-coherent per-XCD L2s); dispatch boundary gives ordering.
// g_part is .bss (zero at load); finalize re-zeroes it each call -> the
// zero-at-entry invariant holds on every graph replay. d_ws unused.

#define NIDS    33               // ids 0..32 (0 = background)
#define HSIZE   (NIDS * NIDS)    // 1089
#define NSLOT   545              // u64 slots covering 1089 u32 bins
#define RSTR64  576              // slot stride padded to 64B-line multiple
#define NREP    4                // histogram replicas at the LLC

__device__ __align__(16) unsigned long long g_part[NREP * RSTR64];  // zero-init, self-cleaned

__device__ __forceinline__ void bin1(unsigned* sh, float p, float t) {
    // p,t are exact integers in [0,32] (randint -> float). p*33+t <= 1088 is
    // exact in f32. Single clamp keeps memory-safety under poisoned inputs
    // (fmax(NaN,0)=0 per IEEE, so even NaN lands in-bounds).
    float f = fminf(fmaxf(p * 33.0f + t, 0.0f), 1088.0f);  // v_med3_f32
    atomicAdd(&sh[(unsigned)f], 1u);
}

__device__ __forceinline__ void bin4(unsigned* sh, float4 p, float4 t) {
    bin1(sh, p.x, t.x);
    bin1(sh, p.y, t.y);
    bin1(sh, p.z, t.z);
    bin1(sh, p.w, t.w);
}

__global__ void __launch_bounds__(1024)
hist_kernel(const float4* __restrict__ pred,
            const float4* __restrict__ tmask, int n4) {
    __shared__ unsigned sh[HSIZE];

    const int tid = threadIdx.x;
    for (int i = tid; i < HSIZE; i += blockDim.x) sh[i] = 0u;
    __syncthreads();

    // per-block LDS histogram, 4-way unrolled float4 loads (8 loads in flight)
    const int tot = gridDim.x * blockDim.x;   // 262144 -> exactly 4 float4/thread
    int i = blockIdx.x * blockDim.x + tid;
    for (; i + 3 * tot < n4; i += 4 * tot) {
        float4 p0 = pred[i],           t0 = tmask[i];
        float4 p1 = pred[i + tot],     t1 = tmask[i + tot];
        float4 p2 = pred[i + 2 * tot], t2 = tmask[i + 2 * tot];
        float4 p3 = pred[i + 3 * tot], t3 = tmask[i + 3 * tot];
        bin4(sh, p0, t0);
        bin4(sh, p1, t1);
        bin4(sh, p2, t2);
        bin4(sh, p3, t3);
    }
    for (; i < n4; i += tot) bin4(sh, pred[i], tmask[i]);
    __syncthreads();

    // flush to replica (blockIdx & 3): u64-packed agent-scope atomics at the
    // LLC. No fence — the dispatch boundary orders this vs finalize_kernel.
    unsigned long long* rep = &g_part[(blockIdx.x & (NREP - 1)) * RSTR64];
    for (int s = tid; s < NSLOT; s += blockDim.x) {
        unsigned lo = sh[2 * s];
        unsigned hi = (2 * s + 1 < HSIZE) ? sh[2 * s + 1] : 0u;
        unsigned long long v = (unsigned long long)lo |
                               ((unsigned long long)hi << 32);
        if (v) atomicAdd(rep + s, v);
    }
}

__global__ void __launch_bounds__(1024)
finalize_kernel(float* __restrict__ out) {
    __shared__ float shf[HSIZE];
    __shared__ float rowsum[NIDS], colsum[NIDS];
    __shared__ float maxv[32];

    const int tid = threadIdx.x;
    // reduce 4 replicas (agent-scope loads at LLC — always coherent).
    // u64 halves can't cross-carry: each half's total <= 4.19M.
    for (int s = tid; s < NSLOT; s += blockDim.x) {
        unsigned long long acc = 0ull;
        #pragma unroll
        for (int r = 0; r < NREP; ++r)
            acc += __hip_atomic_load(&g_part[r * RSTR64 + s], __ATOMIC_RELAXED,
                                     __HIP_MEMORY_SCOPE_AGENT);
        shf[2 * s] = (float)(unsigned)acc;
        if (2 * s + 1 < HSIZE) shf[2 * s + 1] = (float)(unsigned)(acc >> 32);
    }
    // all loads done before anyone zeroes (reduce/zero cover different
    // slot->thread mappings — without this barrier a fast wave could zero a
    // word a slow wave hasn't loaded yet)
    __syncthreads();
    // re-zero for next call: agent-scope stores -> land at LLC, next call's
    // flush atomics see them
    for (int j = tid; j < NREP * RSTR64; j += blockDim.x)
        __hip_atomic_store(&g_part[j], 0ull, __ATOMIC_RELAXED,
                           __HIP_MEMORY_SCOPE_AGENT);
    __syncthreads();

    if (tid < NIDS) {
        float rs = 0.f, cs = 0.f;
        for (int j = 0; j < NIDS; ++j) {
            rs += shf[tid * NIDS + j];
            cs += shf[j * NIDS + tid];
        }
        rowsum[tid] = rs;
        colsum[tid] = cs;
    }
    __syncthreads();

    if (tid < 32) {
        const int n = tid + 1;  // pred instance 1..32
        float best = 0.f;
        const float rs = rowsum[n];
        for (int m = 1; m < NIDS; ++m) {
            float inter = shf[n * NIDS + m];
            float uni   = rs + colsum[m] - inter;
            float iou   = (uni > 0.f) ? (inter / uni) : 0.f;
            best = fmaxf(best, iou);
        }
        maxv[tid] = best;
    }
    __syncthreads();

    if (tid == 0) {
        double sp = 0.0, st = 0.0;
        for (int k = 1; k < NIDS; ++k) {
            sp += (double)k * (double)rowsum[k];
            st += (double)k * (double)colsum[k];
        }
        float loss = 0.f;
        for (int k = 0; k < 32; ++k) loss += 1.0f - maxv[k];
        out[0] = loss + (float)((sp + st) * 1e-12);
    }
}

extern "C" void kernel_launch(void* const* d_in, const int* in_sizes, int n_in,
                              void* d_out, int out_size, void* d_ws, size_t ws_size,
                              hipStream_t stream) {
    const float* pred  = (const float*)d_in[0];
    const float* tmask = (const float*)d_in[1];
    float* out = (float*)d_out;

    const int n  = in_sizes[0];  // 2048*2048 = 4194304
    const int n4 = n / 4;

    // 256 blocks x 1024 threads: 1 block/CU, 16 waves/CU; exactly 4 float4
    // pairs per thread; flush = 140K u64 atomics spread over 4 replicas.
    hist_kernel<<<256, 1024, 0, stream>>>((const float4*)pred,
                                          (const float4*)tmask, n4);
    finalize_kernel<<<1, 1024, 0, stream>>>(out);
}